// Round 2
// baseline (676.180 us; speedup 1.0000x reference)
//
#include <hip/hip_runtime.h>
#include <stdint.h>

#define TK_F       4096
#define TK_WPB     4                              // independent waves (rows) per block
#define TK_THREADS (TK_WPB * 64)
#define TK_NBINS   1024                           // top-10-bit histogram
#define TK_HSLOTS  (TK_NBINS + (TK_NBINS >> 5))   // 1056: +1 dword pad per 32 bins
#define TK_CAP     256                            // threshold-bin candidates (~88 expected)
#define TK_BPL     (TK_NBINS / 64)                // 16 bins owned per lane

// order-preserving float<->uint transforms
__device__ __forceinline__ unsigned int tk_f2u(unsigned int b) {
    return b ^ ((unsigned int)(((int)b) >> 31) | 0x80000000u);
}
__device__ __forceinline__ unsigned int tk_u2f(unsigned int u) {
    return u ^ ((~(unsigned int)(((int)u) >> 31)) | 0x80000000u);
}
// padded slot: keeps bank = f(low bits of b) for atomics, de-conflicts strided readback
__device__ __forceinline__ unsigned int tk_slot(unsigned int b) {
    return b + (b >> 5);
}

__global__ __launch_bounds__(TK_THREADS, 7)
void tk_topk_mask(const float* __restrict__ x, const int* __restrict__ kp,
                  float* __restrict__ out, int B)
{
    // per-wave private state -> no __syncthreads anywhere
    __shared__ uint4        hist4[TK_WPB][TK_HSLOTS / 4];   // 1056 dwords/wave
    __shared__ unsigned int cand[TK_WPB][TK_CAP];
    __shared__ unsigned int cnt[TK_WPB];

    const int lane = (int)(threadIdx.x & 63u);
    const int wid  = (int)(threadIdx.x >> 6);
    const int row  = blockIdx.x * TK_WPB + wid;
    if (row >= B) return;

    const unsigned int k = (unsigned int)kp[0];
    unsigned int* hw = (unsigned int*)hist4[wid];

    const unsigned int* xr   = (const unsigned int*)(x + (size_t)row * TK_F);
    unsigned int*       orow = (unsigned int*)(out + (size_t)row * TK_F);
    const uint4*        xv   = (const uint4*)xr;

    // clear this wave's histogram (uint4 writes; wave-private, in-order LDS)
    const uint4 z = make_uint4(0u, 0u, 0u, 0u);
    #pragma unroll
    for (int i = 0; i < 4; ++i)
        hist4[wid][lane + i * 64] = z;
    if (lane < (TK_HSLOTS / 4 - 256))            // 264 - 256 = 8 tail vectors
        hist4[wid][256 + lane] = z;
    if (lane == 0) cnt[wid] = 0u;

    // ---- pass A: stream row, build 10-bit histogram (values not retained) ----
    #pragma unroll 4
    for (int v = 0; v < 16; ++v) {
        const uint4 t = xv[lane + v * 64];
        atomicAdd(&hw[tk_slot(tk_f2u(t.x) >> 22)], 1u);
        atomicAdd(&hw[tk_slot(tk_f2u(t.y) >> 22)], 1u);
        atomicAdd(&hw[tk_slot(tk_f2u(t.z) >> 22)], 1u);
        atomicAdd(&hw[tk_slot(tk_f2u(t.w) >> 22)], 1u);
    }

    // ---- scan: lane owns bins [lane*16, lane*16+16) ----
    // slot(base+j) = base + (base>>5) + j for j<16 -> 16 consecutive dwords,
    // start offset 16*lane + (lane>>1): 32 distinct banks, 2 lanes/bank = free.
    const unsigned int bbase = (unsigned int)lane * TK_BPL;
    const unsigned int sb    = tk_slot(bbase);
    unsigned int s = 0;
    #pragma unroll
    for (int j = 0; j < TK_BPL; ++j) s += hw[sb + j];

    // inclusive suffix sum of s across lanes (higher lane = higher bins)
    unsigned int acc = s;
    #pragma unroll
    for (int d = 1; d < 64; d <<= 1) {
        const unsigned int t = (unsigned int)__shfl_down((int)acc, (unsigned int)d, 64);
        if (lane + d < 64) acc += t;
    }
    const unsigned int above = acc - s;     // elements in lane-blocks strictly above mine

    // locate the lane-block containing the k-th element
    const unsigned long long bal = __ballot((above < k) && (acc >= k));
    int b = -1;
    unsigned int cum = 0;
    if (bal != 0ull) {
        const int wl = __ffsll((unsigned long long)bal) - 1;
        const unsigned int A = (unsigned int)__shfl((int)above, wl, 64);
        // lanes 0..15 read the winner's 16 bins (consecutive dwords, conflict-free)
        unsigned int hl = 0;
        if (lane < TK_BPL)
            hl = hw[tk_slot((unsigned int)wl * TK_BPL) + (unsigned int)lane];
        unsigned int a2 = hl;
        #pragma unroll
        for (int d = 1; d < TK_BPL; d <<= 1) {
            const unsigned int t = (unsigned int)__shfl_down((int)a2, (unsigned int)d, 64);
            if (lane + d < TK_BPL) a2 += t;
        }
        const unsigned int run = A + (a2 - hl);   // strictly above bin (wl*16+lane)
        const unsigned long long bal2 =
            __ballot((lane < TK_BPL) && (run < k) && (run + hl >= k));
        const int wb = __ffsll((unsigned long long)bal2) - 1;
        b   = wl * TK_BPL + wb;
        cum = (unsigned int)__shfl((int)run, wb, 64);
    }

    if (b < 0) {
        // k >= row length: pure copy
        #pragma unroll 4
        for (int v = 0; v < 16; ++v)
            ((uint4*)orow)[lane + v * 64] = xv[lane + v * 64];
        return;
    }

    // ---- pass B: re-stream row (L2-hot), collect threshold-bin candidates ----
    const unsigned int bb = (unsigned int)b;
    #pragma unroll 4
    for (int v = 0; v < 16; ++v) {
        const uint4 t = xv[lane + v * 64];
        unsigned int uu;
        uu = tk_f2u(t.x);
        if ((uu >> 22) == bb) { const unsigned int p = atomicAdd(&cnt[wid], 1u); if (p < TK_CAP) cand[wid][p] = uu; }
        uu = tk_f2u(t.y);
        if ((uu >> 22) == bb) { const unsigned int p = atomicAdd(&cnt[wid], 1u); if (p < TK_CAP) cand[wid][p] = uu; }
        uu = tk_f2u(t.z);
        if ((uu >> 22) == bb) { const unsigned int p = atomicAdd(&cnt[wid], 1u); if (p < TK_CAP) cand[wid][p] = uu; }
        uu = tk_f2u(t.w);
        if ((uu >> 22) == bb) { const unsigned int p = atomicAdd(&cnt[wid], 1u); if (p < TK_CAP) cand[wid][p] = uu; }
    }

    unsigned int L = cnt[wid];
    if (L > TK_CAP) L = TK_CAP;
    const unsigned int r = k - cum;         // 1-based rank needed inside bin b

    // O(L^2) rank select among candidates (L ~ 88); inner reads are LDS broadcasts
    unsigned int Tl = 0, gl = 0, el = 0;
    int found = 0;
    for (unsigned int j = (unsigned int)lane; j < L; j += 64u) {
        const unsigned int uj = cand[wid][j];
        unsigned int g = 0, eq = 0;
        for (unsigned int i = 0; i < L; ++i) {
            const unsigned int ui = cand[wid][i];
            g  += (ui > uj)  ? 1u : 0u;
            eq += (ui == uj) ? 1u : 0u;
        }
        if (g < r && g + eq >= r) { Tl = uj; gl = g; el = eq; found = 1; }
    }
    const unsigned long long bal3 = __ballot(found);
    const int wt = __ffsll((unsigned long long)bal3) - 1;
    const unsigned int T  = (unsigned int)__shfl((int)Tl, wt, 64);
    const unsigned int g0 = (unsigned int)__shfl((int)gl, wt, 64);
    const unsigned int e0 = (unsigned int)__shfl((int)el, wt, 64);
    const unsigned int re = r - g0;         // # equal-to-T elements to include
    const bool easy = (e0 == re);           // no tie straddling the cut (common case)

    // ---- pass C: re-stream row (L2-hot), threshold, write ----
    #pragma unroll 4
    for (int v = 0; v < 16; ++v) {
        const uint4 t = xv[lane + v * 64];
        uint4 q;
        #pragma unroll
        for (int j = 0; j < 4; ++j) {
            const unsigned int raw = (&t.x)[j];
            const unsigned int uu  = tk_f2u(raw);
            unsigned int val = 0u;
            if (uu > T) {
                val = raw;
            } else if (uu == T) {
                if (easy) {
                    val = raw;
                } else {
                    // rare: duplicated value straddles the cut -> lowest indices win
                    const int idx = (lane + v * 64) * 4 + j;
                    unsigned int c2 = 0;
                    for (int i = 0; i < idx; ++i)
                        c2 += (tk_f2u(xr[i]) == T) ? 1u : 0u;
                    if (c2 < re) val = raw;
                }
            }
            (&q.x)[j] = val;
        }
        ((uint4*)orow)[lane + v * 64] = q;
    }
}

extern "C" void kernel_launch(void* const* d_in, const int* in_sizes, int n_in,
                              void* d_out, int out_size, void* d_ws, size_t ws_size,
                              hipStream_t stream) {
    const float* x   = (const float*)d_in[0];
    const int*   kp  = (const int*)d_in[1];
    float*       out = (float*)d_out;
    const int B = in_sizes[0] / TK_F;
    hipLaunchKernelGGL(tk_topk_mask, dim3((B + TK_WPB - 1) / TK_WPB), dim3(TK_THREADS),
                       0, stream, x, kp, out, B);
}

// Round 3
// 527.898 us; speedup vs baseline: 1.2809x; 1.2809x over previous
//
#include <hip/hip_runtime.h>
#include <stdint.h>

#define TK_F       4096
#define TK_THREADS 256
#define TK_EPT     16                             // elements per thread
#define TK_NBINS   2048                           // top-11-bit histogram
#define TK_HSLOTS  (TK_NBINS + (TK_NBINS >> 5))   // 2112: +1 dword pad per 32 bins
#define TK_CAP     256                            // threshold-bin candidates (~34 expected)

// order-preserving float<->uint transforms
__device__ __forceinline__ unsigned int tk_f2u(unsigned int b) {
    return b ^ ((unsigned int)(((int)b) >> 31) | 0x80000000u);
}
__device__ __forceinline__ unsigned int tk_u2f(unsigned int u) {
    return u ^ ((~(unsigned int)(((int)u) >> 31)) | 0x80000000u);
}
// padded slot: bank(atomic) still spread by mantissa low bits; strided scan reads
// become 2 lanes/bank (free)
__device__ __forceinline__ unsigned int tk_slot(unsigned int b) {
    return b + (b >> 5);
}

__global__ __launch_bounds__(TK_THREADS, 8)       // 8 blocks/CU = 32 waves/CU
void tk_topk_mask(const float* __restrict__ x, const int* __restrict__ kp,
                  float* __restrict__ out, int B)
{
    __shared__ unsigned int hist[TK_HSLOTS];      // 8448 B
    __shared__ unsigned int cand[TK_CAP];         // 1024 B
    __shared__ unsigned int waveTot[TK_THREADS / 64];
    __shared__ unsigned int sh_cnt;
    __shared__ int          sh_b;
    __shared__ unsigned int sh_cum;
    __shared__ unsigned int sh_T, sh_g, sh_e;

    const int tid = threadIdx.x;
    const int row = blockIdx.x;
    if (row >= B) return;
    const unsigned int k = (unsigned int)kp[0];

    const unsigned int* xr   = (const unsigned int*)(x + (size_t)row * TK_F);
    unsigned int*       orow = (unsigned int*)(out + (size_t)row * TK_F);
    const uint4*        xv   = (const uint4*)xr;

    // issue the row loads FIRST: ~900-cycle HBM latency hides under the LDS clear
    unsigned int u[TK_EPT];
    #pragma unroll
    for (int v = 0; v < 4; ++v) {
        uint4 q = xv[tid + v * TK_THREADS];
        u[v*4+0] = tk_f2u(q.x);
        u[v*4+1] = tk_f2u(q.y);
        u[v*4+2] = tk_f2u(q.z);
        u[v*4+3] = tk_f2u(q.w);
    }

    // clear LDS state (2112 dwords / 256 threads)
    #pragma unroll
    for (int i = 0; i < 8; ++i) hist[tid + i * TK_THREADS] = 0u;
    if (tid < TK_HSLOTS - 8 * TK_THREADS) hist[8 * TK_THREADS + tid] = 0u;
    if (tid == 0) { sh_cnt = 0u; sh_b = -1; }
    __syncthreads();   // hist cleared

    // 11-bit histogram (LDS atomics)
    #pragma unroll
    for (int e = 0; e < TK_EPT; ++e)
        atomicAdd(&hist[tk_slot(u[e] >> 21)], 1u);
    __syncthreads();

    // suffix scan: thread t owns bins [8t, 8t+8).
    // slot(8t+j) = slot(8t)+j for j<8 (8t%32 <= 24), so reads are consecutive;
    // across 64 lanes start offsets hit every bank exactly twice -> conflict-free.
    unsigned int hbin[8];
    unsigned int s = 0;
    const unsigned int sbase = tk_slot((unsigned int)tid * 8u);
    #pragma unroll
    for (int j = 0; j < 8; ++j) { hbin[j] = hist[sbase + j]; s += hbin[j]; }

    // wave-level inclusive suffix sum of s
    unsigned int acc = s;
    const int lane = tid & 63;
    #pragma unroll
    for (int d = 1; d < 64; d <<= 1) {
        unsigned int v = (unsigned int)__shfl_down((int)acc, d, 64);
        if (lane + d < 64) acc += v;
    }
    const int wid = tid >> 6;
    if (lane == 0) waveTot[wid] = acc;     // lane0 suffix == wave total
    __syncthreads();
    unsigned int later = 0;
    #pragma unroll
    for (int w = 0; w < TK_THREADS / 64; ++w)
        if (w > wid) later += waveTot[w];

    // count of elements in bins strictly above my highest bin
    unsigned int run = later + (acc - s);
    #pragma unroll
    for (int j = 7; j >= 0; --j) {
        unsigned int h = hbin[j];
        if (run < k && run + h >= k) { sh_b = tid * 8 + j; sh_cum = run; }
        run += h;
    }
    __syncthreads();

    const int b = sh_b;
    if (b < 0) {
        // k >= row length: everything passes through
        #pragma unroll
        for (int v = 0; v < 4; ++v) {
            uint4 q;
            q.x = tk_u2f(u[v*4+0]); q.y = tk_u2f(u[v*4+1]);
            q.z = tk_u2f(u[v*4+2]); q.w = tk_u2f(u[v*4+3]);
            ((uint4*)orow)[tid + v * TK_THREADS] = q;
        }
        return;
    }
    const unsigned int cum = sh_cum;          // # elements strictly above bin b

    // collect candidates (elements whose top-11 bits == b)
    #pragma unroll
    for (int e = 0; e < TK_EPT; ++e) {
        if ((int)(u[e] >> 21) == b) {
            unsigned int p = atomicAdd(&sh_cnt, 1u);
            if (p < TK_CAP) cand[p] = u[e];
        }
    }
    __syncthreads();

    const unsigned int L = (sh_cnt < TK_CAP) ? sh_cnt : TK_CAP;
    const unsigned int r = k - cum;           // rank needed inside bin b (1-based)
    for (unsigned int j = tid; j < L; j += TK_THREADS) {
        unsigned int uj = cand[j];
        unsigned int g = 0, eq = 0;
        for (unsigned int i = 0; i < L; ++i) {
            unsigned int ui = cand[i];        // broadcast read
            g  += (ui > uj)  ? 1u : 0u;
            eq += (ui == uj) ? 1u : 0u;
        }
        if (g < r && g + eq >= r) { sh_T = uj; sh_g = g; sh_e = eq; }
    }
    __syncthreads();

    const unsigned int T  = sh_T;
    const unsigned int re = r - sh_g;         // # equal-to-T elements to include
    const unsigned int ce = sh_e;             // total equal-to-T elements in row
    const bool easy = (ce == re);             // no tie at the cut (overwhelmingly common)

    #pragma unroll
    for (int v = 0; v < 4; ++v) {
        uint4 q;
        #pragma unroll
        for (int j = 0; j < 4; ++j) {
            unsigned int uu  = u[v*4+j];
            unsigned int val = 0u;
            if (uu > T) {
                val = tk_u2f(uu);
            } else if (uu == T) {
                if (easy) {
                    val = tk_u2f(uu);
                } else {
                    // rare: duplicated value straddles the cut -> lowest indices win.
                    int idx = (tid + v * TK_THREADS) * 4 + j;
                    unsigned int cnt = 0;
                    for (int i = 0; i < idx; ++i)
                        cnt += (tk_f2u(xr[i]) == T) ? 1u : 0u;
                    if (cnt < re) val = tk_u2f(uu);
                }
            }
            (&q.x)[j] = val;
        }
        ((uint4*)orow)[tid + v * TK_THREADS] = q;
    }
}

extern "C" void kernel_launch(void* const* d_in, const int* in_sizes, int n_in,
                              void* d_out, int out_size, void* d_ws, size_t ws_size,
                              hipStream_t stream) {
    const float* x   = (const float*)d_in[0];
    const int*   kp  = (const int*)d_in[1];
    float*       out = (float*)d_out;
    const int B = in_sizes[0] / TK_F;
    hipLaunchKernelGGL(tk_topk_mask, dim3(B), dim3(TK_THREADS), 0, stream,
                       x, kp, out, B);
}